// Round 11
// baseline (205.481 us; speedup 1.0000x reference)
//
#include <hip/hip_runtime.h>
#include <stdint.h>

#define IMG_W 512
#define IMG_H 512
#define RH    64            // output rows per block-strip
#define KS    11
#define KR    5
#define OFF   8             // LDS left pad (16B-aligned, stays zero)
#define LROW  (OFF + IMG_W + OFF)   // 528 floats per row buffer
#define CH    KS            // 11 rows per chunk (ring-aligned)
#define NROWS (RH + 2*KR)   // 74 input rows per strip
#define NCH   7             // 7*11 = 77 >= 74

typedef float v2f __attribute__((ext_vector_type(2)));

// One block = 512 threads (8 waves), one 64-row x 512-col strip, 1 col/thread.
// R6-verified structure (single-buffer, 2 barriers/chunk) with a STREAMING
// horizontal pass: each float2 window pair is consumed immediately (2 taps x
// 4 fields) instead of being held in wa[12]/wb[12] arrays — live window regs
// drop 24 -> 4, bringing total pressure under 128 so __launch_bounds__(512,4)
// fits 2 blocks/CU (4 waves/SIMD) WITHOUT AGPR overflow (R9 showed the AGPR
// failure mode: VALU busy-cycles double from v_accvgpr marshaling).
// Fields: U = conv(x), V = conv(xhat), S = conv(x^2+xhat^2), P = conv(x*xhat);
// (v+1)/2 shift folded into the epilogue. Vertical 11-tap on v_pk_fma_f32,
// weights broadcast from SGPR pairs (g,g). Ring phase p is compile-time.
__global__ __launch_bounds__(512, 4)
void ssim_main(const float* __restrict__ xhat,
               const float* __restrict__ x,
               const float* __restrict__ kern,
               float* __restrict__ accum)
{
    __shared__ float rowA[CH][LROW];   // raw x rows, zero-padded cols
    __shared__ float rowB[CH][LROW];   // raw xhat rows
    __shared__ float red[8];

    const int tid   = threadIdx.x;
    const int lane  = tid & 63;
    const int wid   = tid >> 6;          // 8 waves
    const int c     = tid;               // this thread's column
    const int img   = blockIdx.x >> 3;   // 8 strips per image
    const int strip = blockIdx.x & 7;
    const int R0    = strip * RH;
    const float* xp = x    + (size_t)img * (IMG_W * IMG_H);
    const float* hp = xhat + (size_t)img * (IMG_W * IMG_H);

    // Separable 1D weights g[i] = k[5][i]/sqrt(k[5][5]); lane-uniform ->
    // pinned to SGPRs via readfirstlane. gg[i] = (g,g) SGPR pair for pk_fma.
    float  g[KS];
    double gg[KS];
    {
        const float inv = rsqrtf(kern[5 * KS + 5]);
        #pragma unroll
        for (int i = 0; i < KS; ++i) {
            const float v = kern[5 * KS + i] * inv;
            const uint32_t ub = __builtin_amdgcn_readfirstlane(
                                    __builtin_bit_cast(int, v));
            g[i]  = __builtin_bit_cast(float, ub);
            const uint64_t uu = ((uint64_t)ub << 32) | (uint64_t)ub;
            gg[i] = __builtin_bit_cast(double, uu);
        }
    }

    // zero all LDS once (pads must stay 0; interior overwritten each chunk)
    {
        float4* a4 = (float4*)&rowA[0][0];
        float4* b4 = (float4*)&rowB[0][0];
        #pragma unroll 1
        for (int i = tid; i < (CH * LROW) / 4; i += 512) {
            a4[i] = make_float4(0.f, 0.f, 0.f, 0.f);
            b4[i] = make_float4(0.f, 0.f, 0.f, 0.f);
        }
    }

    // ring of horizontally-convolved rows: 2 pair-fields x 11 rows (44 VGPRs)
    v2f uvR[KS];   // (U, V)
    v2f spR[KS];   // (S, P)
    float acc = 0.f;
    const float C1 = 1e-4f, C2 = 9e-4f;

    #pragma unroll 1
    for (int chk = 0; chk < NCH; ++chk) {
        __syncthreads();   // previous chunk fully consumed (also covers zero-init)

        // ---- stage 11 rows x 2 fields, direct global->LDS ----
        // 44 issues = row j (0..10) x field f (A,B) x half h (0,1); wave w
        // takes q = w, w+8, ... Each issue: 64 lanes x 16B, coalesced; LDS
        // dest is wave-uniform base + lane*16 (linear layout). Zero VGPR cost.
        #pragma unroll
        for (int k = 0; k < 6; ++k) {
            const int q = wid + 8 * k;           // wave-uniform
            if (q < 4 * CH) {
                const int j  = q >> 2;
                const int rr = chk * CH + j;
                if (rr < NROWS) {
                    const int f  = (q >> 1) & 1;
                    const int h  = q & 1;
                    const int ri = R0 - KR + rr;
                    float* ldsbase = f ? &rowB[j][OFF + h * 256]
                                       : &rowA[j][OFF + h * 256];
                    if (ri >= 0 && ri < IMG_H) {
                        const float* gsrc = (f ? hp : xp)
                            + (size_t)ri * IMG_W + h * 256 + lane * 4;
                        __builtin_amdgcn_global_load_lds(
                            (const __attribute__((address_space(1))) void*)gsrc,
                            (__attribute__((address_space(3))) void*)ldsbase,
                            16, 0, 0);
                    } else {
                        *(float4*)(ldsbase + lane * 4) =
                            make_float4(0.f, 0.f, 0.f, 0.f);
                    }
                }
            }
        }
        __syncthreads();   // barrier waits vmcnt(0): chunk staged

        // ---- compute 11 rows; ring slot == p (compile-time) ----
        #pragma unroll
        for (int p = 0; p < CH; ++p) {
            const int rr = chk * CH + p;          // block-uniform
            if (rr < NROWS) {
                // streaming horizontal pass over window cols [c-6, c+6):
                // 6 aligned float2 reads; element i=2m feeds tap 2m-1 (skip
                // at m=0), element i=2m+1 feeds tap 2m. Live regs: one
                // float2 pair per field + 2 accumulator pairs.
                const int ib = OFF + c - 6;       // even -> 8B-aligned
                v2f huv; huv.x = 0.f; huv.y = 0.f;   // (U, V)
                v2f hsp; hsp.x = 0.f; hsp.y = 0.f;   // (S, P)
                #pragma unroll
                for (int m = 0; m < 6; ++m) {
                    const float2 ta = *(const float2*)&rowA[p][ib + 2 * m];
                    const float2 tb = *(const float2*)&rowB[p][ib + 2 * m];
                    if (m > 0) {                  // tap 2m-1
                        const float w  = g[2 * m - 1];
                        const float pa = ta.x, pb = tb.x;
                        huv.x = fmaf(w, pa,                    huv.x);
                        huv.y = fmaf(w, pb,                    huv.y);
                        hsp.x = fmaf(w, fmaf(pb, pb, pa * pa), hsp.x);
                        hsp.y = fmaf(w, pa * pb,               hsp.y);
                    }
                    {                             // tap 2m
                        const float w  = g[2 * m];
                        const float pa = ta.y, pb = tb.y;
                        huv.x = fmaf(w, pa,                    huv.x);
                        huv.y = fmaf(w, pb,                    huv.y);
                        hsp.x = fmaf(w, fmaf(pb, pb, pa * pa), hsp.x);
                        hsp.y = fmaf(w, pa * pb,               hsp.y);
                    }
                }
                uvR[p] = huv;
                spR[p] = hsp;

                // ---- vertical pass (packed dual-f32) + SSIM ----
                if (rr >= 2 * KR) {
                    v2f UV; UV.x = 0.f; UV.y = 0.f;
                    v2f SP; SP.x = 0.f; SP.y = 0.f;
                    #pragma unroll
                    for (int t = 0; t < KS; ++t) {
                        const int slot = (p + 1 + t) % KS;   // compile-time
                        asm("v_pk_fma_f32 %0, %1, %2, %0"
                            : "+v"(UV) : "s"(gg[t]), "v"(uvR[slot]));
                        asm("v_pk_fma_f32 %0, %1, %2, %0"
                            : "+v"(SP) : "s"(gg[t]), "v"(spR[slot]));
                    }
                    const float U = UV.x, V = UV.y, S = SP.x, P = SP.y;
                    // epilogue on raw-field moments (shift folded in):
                    //   2 mu_x mu_y + C1   = 0.5 pU pV + C1
                    //   2 sig_xy + C2      = 0.5 (P - U V) + C2
                    //   mu_x^2+mu_y^2+C1   = 0.25 (pU^2 + pV^2) + C1
                    //   sig_x+sig_y+C2     = 0.25 (S - U^2 - V^2) + C2
                    const float pU = U + 1.f, pV = V + 1.f;
                    const float t1 = fmaf(0.5f,  pU * pV,              C1);
                    const float t2 = fmaf(0.5f,  fmaf(-U, V, P),       C2);
                    const float t3 = fmaf(0.25f, fmaf(pU, pU, pV * pV), C1);
                    const float e  = fmaf(-V, V, fmaf(-U, U, S));
                    const float t4 = fmaf(0.25f, e,                    C2);
                    acc = fmaf(t1 * t2,
                               __builtin_amdgcn_rcpf(fmaf(t3, t4, 1e-8f)),
                               acc);
                }
            }
        }
    }

    // ---- block reduction: wave shuffle, then LDS across the 8 waves ----
    #pragma unroll
    for (int o = 32; o > 0; o >>= 1) acc += __shfl_down(acc, o, 64);
    if (lane == 0) red[wid] = acc;
    __syncthreads();
    if (tid == 0) {
        float s = 0.f;
        #pragma unroll
        for (int w = 0; w < 8; ++w) s += red[w];
        atomicAdd(accum, s);
    }
}

__global__ void ssim_final(const float* __restrict__ accum,
                           float* __restrict__ out)
{
    out[0] = 1.0f - accum[0] * (1.0f / (64.0f * 512.0f * 512.0f));
}

extern "C" void kernel_launch(void* const* d_in, const int* in_sizes, int n_in,
                              void* d_out, int out_size, void* d_ws, size_t ws_size,
                              hipStream_t stream) {
    const float* xhat = (const float*)d_in[0];
    const float* xin  = (const float*)d_in[1];
    const float* kern = (const float*)d_in[2];
    float* out = (float*)d_out;
    float* ws  = (float*)d_ws;

    const int nimg   = in_sizes[0] / (IMG_W * IMG_H);   // 64
    const int strips = IMG_H / RH;                      // 8
    const int nblk   = nimg * strips;                   // 512 = 2 blocks/CU

    hipMemsetAsync(ws, 0, sizeof(float), stream);
    ssim_main<<<nblk, 512, 0, stream>>>(xhat, xin, kern, ws);
    ssim_final<<<1, 1, 0, stream>>>(ws, out);
}